// Round 1
// baseline (1422.301 us; speedup 1.0000x reference)
//
#include <hip/hip_runtime.h>
#include <math.h>

#define NPG 100
#define KTOP 60
#define DLAT 97

static __device__ __forceinline__ float dot4(float4 a, float4 b){
  return a.x*b.x + a.y*b.y + a.z*b.z + a.w*b.w;
}

// ---------------- prep ----------------
__global__ void k_deg_cnt(const int* __restrict__ dst, const float* __restrict__ ew,
                          float* deg, int* cnt, int E){
  int e = blockIdx.x*256 + threadIdx.x;
  if(e < E){
    int d = dst[e];
    atomicAdd(&deg[d], ew[e]);
    atomicAdd(&cnt[d], 1);
  }
}

__global__ void k_dis(float* deg, int N){
  int n = blockIdx.x*256 + threadIdx.x;
  if(n < N) deg[n] = rsqrtf(deg[n] + 1.0f);   // self-loop weight 1 included; deg>=1
}

__global__ void k_scan_a(const int* __restrict__ cnt, int* rs, int* bsum, int N){
  __shared__ int s[256];
  int g = blockIdx.x*256 + threadIdx.x;
  int v = (g < N) ? cnt[g] : 0;
  s[threadIdx.x] = v;
  __syncthreads();
  for(int off=1; off<256; off<<=1){
    int t = (threadIdx.x >= off) ? s[threadIdx.x-off] : 0;
    __syncthreads();
    s[threadIdx.x] += t;
    __syncthreads();
  }
  if(g < N) rs[g] = s[threadIdx.x] - v;          // exclusive within block
  if(threadIdx.x == 255) bsum[blockIdx.x] = s[255];
}

__global__ void k_scan_b(int* bsum, int nb){     // nb <= 1024
  __shared__ int s[1024];
  int v = (threadIdx.x < nb) ? bsum[threadIdx.x] : 0;
  s[threadIdx.x] = v;
  __syncthreads();
  for(int off=1; off<1024; off<<=1){
    int t = (threadIdx.x >= off) ? s[threadIdx.x-off] : 0;
    __syncthreads();
    s[threadIdx.x] += t;
    __syncthreads();
  }
  if(threadIdx.x < nb) bsum[threadIdx.x] = s[threadIdx.x] - v;  // exclusive
}

__global__ void k_scan_c(int* rs, int* cursor, const int* __restrict__ bsum, int N, int E){
  int g = blockIdx.x*256 + threadIdx.x;
  if(g < N){
    int v = rs[g] + bsum[blockIdx.x];
    rs[g] = v;
    cursor[g] = v;
  }
  if(g == 0) rs[N] = E;
}

__global__ void k_fill(const int* __restrict__ src, const int* __restrict__ dst,
                       const float* __restrict__ ew, const float* __restrict__ dis,
                       int* cursor, int* csr_src, float* csr_norm, int E){
  int e = blockIdx.x*256 + threadIdx.x;
  if(e < E){
    int s = src[e], d = dst[e];
    int p = atomicAdd(&cursor[d], 1);
    csr_src[p] = s;
    csr_norm[p] = dis[s]*ew[e]*dis[d];
  }
}

// ---------------- GEMMs ----------------
// layer1: x0(=concat of 3 embedding gathers)[N,96] @ W0[96,32]
__global__ __launch_bounds__(256) void k_gemm1(const int* __restrict__ wI, const int* __restrict__ z1I,
   const int* __restrict__ z2I,
   const float* __restrict__ embw, const float* __restrict__ embz1, const float* __restrict__ embz2,
   const float* __restrict__ W0, float* __restrict__ hx, int N){
  __shared__ __align__(16) float X[128][97];   // stride 97: bank-conflict-free for 4-node strided reads
  __shared__ __align__(16) float Ws[96*32];
  __shared__ int iw[128], i1[128], i2[128];
  int tid = threadIdx.x;
  int g0 = blockIdx.x*128;
  for(int i=tid;i<96*32;i+=256) Ws[i]=W0[i];
  if(tid < 128){
    int gn = g0 + tid;
    bool ok = gn < N;
    iw[tid] = ok ? wI[gn]  : 0;
    i1[tid] = ok ? z1I[gn] : 0;
    i2[tid] = ok ? z2I[gn] : 0;
  }
  __syncthreads();
  for(int r=0;r<48;r++){
    int flat = r*256 + tid;
    int n = flat/96, c = flat - n*96;
    int gn = g0 + n;
    float val = 0.f;
    if(gn < N){
      if(c < 32)      val = embw [iw[n]*32 + c];
      else if(c < 64) val = embz1[i1[n]*32 + (c-32)];
      else            val = embz2[i2[n]*32 + (c-64)];
    }
    X[n][c] = val;
  }
  __syncthreads();
  int ng = tid>>3, chg = tid&7;     // 32 node-groups x 8 channel-groups
  float4 acc[4];
  #pragma unroll
  for(int j=0;j<4;j++) acc[j] = make_float4(0.f,0.f,0.f,0.f);
  #pragma unroll 4
  for(int i=0;i<96;i++){
    float4 wv = *(const float4*)&Ws[i*32 + chg*4];
    #pragma unroll
    for(int j=0;j<4;j++){
      float xv = X[ng*4+j][i];
      acc[j].x += xv*wv.x; acc[j].y += xv*wv.y; acc[j].z += xv*wv.z; acc[j].w += xv*wv.w;
    }
  }
  #pragma unroll
  for(int j=0;j<4;j++){
    int gn = g0 + ng*4 + j;
    if(gn < N) *(float4*)&hx[(size_t)gn*32 + chg*4] = acc[j];
  }
}

// layers 2/3: h[N,32] @ W[32,32]
__global__ __launch_bounds__(256) void k_gemm32(const float* __restrict__ xin, const float* __restrict__ W,
    float* __restrict__ hx, int N){
  __shared__ __align__(16) float X[128][33];
  __shared__ __align__(16) float Ws[32*32];
  int tid = threadIdx.x;
  int g0 = blockIdx.x*128;
  for(int i=tid;i<1024;i+=256) Ws[i]=W[i];
  for(int r=0;r<16;r++){
    int flat = r*256 + tid;
    int n = flat>>5, c = flat&31;
    int gn = g0 + n;
    X[n][c] = (gn < N) ? xin[(size_t)gn*32 + c] : 0.f;
  }
  __syncthreads();
  int ng = tid>>3, chg = tid&7;
  float4 acc[4];
  #pragma unroll
  for(int j=0;j<4;j++) acc[j] = make_float4(0.f,0.f,0.f,0.f);
  #pragma unroll 4
  for(int i=0;i<32;i++){
    float4 wv = *(const float4*)&Ws[i*32 + chg*4];
    #pragma unroll
    for(int j=0;j<4;j++){
      float xv = X[ng*4+j][i];
      acc[j].x += xv*wv.x; acc[j].y += xv*wv.y; acc[j].z += xv*wv.z; acc[j].w += xv*wv.w;
    }
  }
  #pragma unroll
  for(int j=0;j<4;j++){
    int gn = g0 + ng*4 + j;
    if(gn < N) *(float4*)&hx[(size_t)gn*32 + chg*4] = acc[j];
  }
}

// layer4: h3[N,32] @ W3[32,1]
__global__ __launch_bounds__(256) void k_gemmv(const float* __restrict__ xin, const float* __restrict__ W3,
    float* __restrict__ hv, int N){
  __shared__ float X[256][33];
  __shared__ float Ws[32];
  int tid = threadIdx.x;
  int g0 = blockIdx.x*256;
  if(tid < 32) Ws[tid] = W3[tid];
  for(int r=0;r<32;r++){
    int flat = r*256 + tid;
    int n = flat>>5, c = flat&31;
    int gn = g0 + n;
    X[n][c] = (gn < N) ? xin[(size_t)gn*32 + c] : 0.f;
  }
  __syncthreads();
  float acc = 0.f;
  #pragma unroll
  for(int i=0;i<32;i++) acc += X[tid][i]*Ws[i];
  int gn = g0 + tid;
  if(gn < N) hv[gn] = acc;
}

// ---------------- aggregation (gather CSR by dst) ----------------
__global__ __launch_bounds__(256) void k_agg32(const float* __restrict__ hx, const float* __restrict__ dis,
   const int* __restrict__ rs, const int* __restrict__ csr_src, const float* __restrict__ csr_norm,
   const float* __restrict__ bias, float* __restrict__ hout, int N){
  int tid = threadIdx.x;
  int ln = tid>>5, ch = tid&31;
  int n = blockIdx.x*8 + ln;
  if(n >= N) return;
  float dn = dis[n];
  float acc = dn*dn*hx[(size_t)n*32 + ch];   // self loop
  int e0 = rs[n], e1 = rs[n+1];
  for(int e=e0;e<e1;e++){
    int s = csr_src[e];
    float nrm = csr_norm[e];
    acc += nrm * hx[(size_t)s*32 + ch];
  }
  hout[(size_t)n*32 + ch] = tanhf(acc + bias[ch]);
}

__global__ void k_agg1(const float* __restrict__ hv, const float* __restrict__ dis,
   const int* __restrict__ rs, const int* __restrict__ csr_src, const float* __restrict__ csr_norm,
   const float* __restrict__ b3, float* __restrict__ h4, int N){
  int n = blockIdx.x*256 + threadIdx.x;
  if(n >= N) return;
  float dn = dis[n];
  float acc = dn*dn*hv[n];
  int e0 = rs[n], e1 = rs[n+1];
  for(int e=e0;e<e1;e++) acc += csr_norm[e]*hv[csr_src[e]];
  h4[n] = tanhf(acc + b3[0]);
}

// ---------------- fused head: sortpool + conv1 + pool + conv2 + l1 + l2 ----------------
__global__ __launch_bounds__(256) void k_head(const float* __restrict__ h1,const float* __restrict__ h2,
  const float* __restrict__ h3,const float* __restrict__ h4,
  const float* __restrict__ c1W,const float* __restrict__ c1b,
  const float* __restrict__ c2W,const float* __restrict__ c2b,
  const float* __restrict__ l1W,const float* __restrict__ l1b,
  const float* __restrict__ l2W,const float* __restrict__ l2b,
  float* __restrict__ out){
  __shared__ float v[100];
  __shared__ int ord[KTOP];
  __shared__ __align__(16) float xk[KTOP][100];    // rows padded to 100 for float4 alignment
  __shared__ __align__(16) float c1Ws[16*100];
  __shared__ __align__(16) float t1[16][60];
  __shared__ __align__(16) float t2[16][32];
  __shared__ __align__(16) float c2Ws[32*16*5];
  __shared__ __align__(16) float flat[832];
  __shared__ __align__(16) float o1s[2][128];
  int b = blockIdx.x, tid = threadIdx.x;
  int g0 = b*NPG;
  for(int i=tid;i<16*97;i+=256){ int o=i/97, d=i-o*97; c1Ws[o*100+d]=c1W[i]; }
  for(int i=tid;i<2560;i+=256) c2Ws[i]=c2W[i];
  if(tid < 100) v[tid] = h4[g0+tid];
  __syncthreads();
  // stable descending rank == jnp.argsort(-v) (stable)
  if(tid < 100){
    float vi = v[tid];
    int rank = 0;
    for(int j=0;j<100;j++){
      float vj = v[j];
      rank += (vj > vi) || (vj == vi && j < tid);
    }
    if(rank < KTOP) ord[rank] = tid;
  }
  __syncthreads();
  // gather top-K rows: x = [h1|h2|h3|h4]
  for(int idx=tid; idx<KTOP*DLAT; idx+=256){
    int k = idx/DLAT, d = idx - k*DLAT;
    int n = g0 + ord[k];
    float val;
    if(d < 32)      val = h1[(size_t)n*32 + d];
    else if(d < 64) val = h2[(size_t)n*32 + (d-32)];
    else if(d < 96) val = h3[(size_t)n*32 + (d-64)];
    else            val = h4[n];
    xk[k][d] = val;
  }
  __syncthreads();
  // conv1: t1[o][k] = relu(sum_d xk[k][d]*c1W[o][d] + c1b[o]); 120 threads: 8 og x 15 kg
  if(tid < 120){
    int og = tid/15, kg = tid - og*15;     // o in {og, og+8}; k = kg + 15*j (bank-friendly)
    float a0[4] = {0,0,0,0}, a1[4] = {0,0,0,0};
    for(int d=0; d<96; d+=4){
      float4 w0 = *(const float4*)&c1Ws[og*100 + d];
      float4 w1 = *(const float4*)&c1Ws[(og+8)*100 + d];
      #pragma unroll
      for(int j=0;j<4;j++){
        float4 xv = *(const float4*)&xk[kg + 15*j][d];
        a0[j] += dot4(xv, w0);
        a1[j] += dot4(xv, w1);
      }
    }
    {
      float w0 = c1Ws[og*100 + 96], w1 = c1Ws[(og+8)*100 + 96];
      #pragma unroll
      for(int j=0;j<4;j++){
        float xv = xk[kg + 15*j][96];
        a0[j] += xv*w0;
        a1[j] += xv*w1;
      }
    }
    float b0v = c1b[og], b1v = c1b[og+8];
    #pragma unroll
    for(int j=0;j<4;j++){
      t1[og  ][kg + 15*j] = fmaxf(a0[j] + b0v, 0.f);
      t1[og+8][kg + 15*j] = fmaxf(a1[j] + b1v, 0.f);
    }
  }
  __syncthreads();
  // maxpool(2,2): t2[o][j] = max(t1[o][2j], t1[o][2j+1])
  for(int idx=tid; idx<480; idx+=256){
    int o = idx/30, jj = idx - o*30;
    t2[o][jj] = fmaxf(t1[o][2*jj], t1[o][2*jj+1]);
  }
  __syncthreads();
  // conv2 (k=5, 16->32ch) + relu, write flattened [oc*26+p]
  if(tid < 224){
    int oc = tid/7, pg = tid - oc*7;
    int p0 = pg*4;
    float acc[4] = {0,0,0,0};
    for(int ic=0; ic<16; ic++){
      float4 A  = *(const float4*)&t2[ic][p0];
      float4 Bv = *(const float4*)&t2[ic][p0+4];
      float e[8] = {A.x,A.y,A.z,A.w,Bv.x,Bv.y,Bv.z,Bv.w};
      const float* wr = &c2Ws[(oc*16 + ic)*5];
      #pragma unroll
      for(int q=0;q<4;q++){
        #pragma unroll
        for(int r=0;r<5;r++) acc[q] += e[q+r]*wr[r];
      }
    }
    float bb = c2b[oc];
    #pragma unroll
    for(int q=0;q<4;q++){
      int p = p0 + q;
      if(p < 26) flat[oc*26 + p] = fmaxf(acc[q] + bb, 0.f);
    }
  }
  __syncthreads();
  // l1: [832]@[832,128] + relu ; split i-range over two half-blocks
  {
    int half = tid>>7, j = tid&127;
    int i0 = half*416;
    float s = 0.f;
    #pragma unroll 4
    for(int i=0;i<416;i++){
      s += flat[i0+i] * l1W[(size_t)(i0+i)*128 + j];
    }
    o1s[half][j] = s;
  }
  __syncthreads();
  if(tid < 128){
    float r = o1s[0][tid] + o1s[1][tid] + l1b[tid];
    o1s[0][tid] = fmaxf(r, 0.f);
  }
  __syncthreads();
  // l2: dot(o1, l2W) + b
  float* red = (float*)t1;
  if(tid < 128) red[tid] = o1s[0][tid]*l2W[tid];
  __syncthreads();
  if(tid < 64){
    float val = red[tid] + red[tid+64];
    #pragma unroll
    for(int off=32; off>0; off>>=1) val += __shfl_down(val, off);
    if(tid == 0) out[b] = val + l2b[0];
  }
}

// ---------------- launch ----------------
extern "C" void kernel_launch(void* const* d_in, const int* in_sizes, int n_in,
                              void* d_out, int out_size, void* d_ws, size_t ws_size,
                              hipStream_t stream){
  (void)n_in; (void)out_size; (void)ws_size;
  const int*   z1    = (const int*)  d_in[0];
  const int*   z2    = (const int*)  d_in[1];
  const int*   w     = (const int*)  d_in[2];
  const int*   eidx  = (const int*)  d_in[3];
  const float* ew    = (const float*)d_in[5];
  const float* embw  = (const float*)d_in[6];
  const float* embz1 = (const float*)d_in[7];
  const float* embz2 = (const float*)d_in[8];
  const float* W0    = (const float*)d_in[9];
  const float* b0    = (const float*)d_in[10];
  const float* W1    = (const float*)d_in[11];
  const float* b1    = (const float*)d_in[12];
  const float* W2    = (const float*)d_in[13];
  const float* b2    = (const float*)d_in[14];
  const float* W3    = (const float*)d_in[15];
  const float* b3    = (const float*)d_in[16];
  const float* c1W   = (const float*)d_in[17];
  const float* c1b   = (const float*)d_in[18];
  const float* c2W   = (const float*)d_in[19];
  const float* c2b   = (const float*)d_in[20];
  const float* l1W   = (const float*)d_in[21];
  const float* l1b   = (const float*)d_in[22];
  const float* l2W   = (const float*)d_in[23];
  const float* l2b   = (const float*)d_in[24];
  float* out = (float*)d_out;

  int N = in_sizes[0];
  int E = in_sizes[3]/2;
  int B = N/NPG;
  const int* src = eidx;
  const int* dst = eidx + E;

  char* p = (char*)d_ws;
  auto alloc = [&](size_t bytes)->char*{
    char* r = p;
    p += (bytes + 255) & ~(size_t)255;
    return r;
  };
  float* h1       = (float*)alloc((size_t)N*32*4);
  float* h2       = (float*)alloc((size_t)N*32*4);
  float* h3       = (float*)alloc((size_t)N*32*4);
  float* h4       = (float*)alloc((size_t)N*4);
  float* hx       = (float*)alloc((size_t)N*32*4);
  float* dis      = (float*)alloc((size_t)N*4);        // deg, then rsqrt in place
  int*   cnt      = (int*)  alloc((size_t)N*4);
  int*   rs       = (int*)  alloc((size_t)(N+1)*4);
  int*   cursor   = (int*)  alloc((size_t)N*4);
  int*   bsum     = (int*)  alloc(4096);
  int*   csr_src  = (int*)  alloc((size_t)E*4);
  float* csr_norm = (float*)alloc((size_t)E*4);

  hipMemsetAsync(dis, 0, (size_t)N*4, stream);
  hipMemsetAsync(cnt, 0, (size_t)N*4, stream);

  int gE = (E+255)/256, gN = (N+255)/256;
  k_deg_cnt<<<gE, 256, 0, stream>>>(dst, ew, dis, cnt, E);
  k_dis<<<gN, 256, 0, stream>>>(dis, N);
  k_scan_a<<<gN, 256, 0, stream>>>(cnt, rs, bsum, N);
  k_scan_b<<<1, 1024, 0, stream>>>(bsum, gN);
  k_scan_c<<<gN, 256, 0, stream>>>(rs, cursor, bsum, N, E);
  k_fill<<<gE, 256, 0, stream>>>(src, dst, ew, dis, cursor, csr_src, csr_norm, E);

  int gG = (N+127)/128;
  k_gemm1<<<gG, 256, 0, stream>>>(w, z1, z2, embw, embz1, embz2, W0, hx, N);
  k_agg32<<<(N+7)/8, 256, 0, stream>>>(hx, dis, rs, csr_src, csr_norm, b0, h1, N);
  k_gemm32<<<gG, 256, 0, stream>>>(h1, W1, hx, N);
  k_agg32<<<(N+7)/8, 256, 0, stream>>>(hx, dis, rs, csr_src, csr_norm, b1, h2, N);
  k_gemm32<<<gG, 256, 0, stream>>>(h2, W2, hx, N);
  k_agg32<<<(N+7)/8, 256, 0, stream>>>(hx, dis, rs, csr_src, csr_norm, b2, h3, N);
  k_gemmv<<<(N+255)/256, 256, 0, stream>>>(h3, W3, hx, N);   // reuse hx[0..N) as h3@W3
  k_agg1<<<gN, 256, 0, stream>>>(hx, dis, rs, csr_src, csr_norm, b3, h4, N);

  k_head<<<B, 256, 0, stream>>>(h1, h2, h3, h4, c1W, c1b, c2W, c2b,
                                l1W, l1b, l2W, l2b, out);
}

// Round 2
// 1084.409 us; speedup vs baseline: 1.3116x; 1.3116x over previous
//
#include <hip/hip_runtime.h>
#include <math.h>

#define NPG 100
#define KTOP 60
#define DLAT 97
#define NB 2000         // buckets = graphs
#define NBLK 512        // binning blocks
#define CPB 6250        // edges per binning block = ceil(3.2M/512)

static __device__ __forceinline__ float dot4(float4 a, float4 b){
  return a.x*b.x + a.y*b.y + a.z*b.z + a.w*b.w;
}

// ---------------- prep: atomic-free CSR build via per-graph bucketing ----------------
__global__ __launch_bounds__(256) void k_hist(const int* __restrict__ dst, int* __restrict__ histG, int E){
  __shared__ int h[NB];
  int blk = blockIdx.x, tid = threadIdx.x;
  for(int i=tid;i<NB;i+=256) h[i]=0;
  __syncthreads();
  int e0 = blk*CPB, e1 = min(e0+CPB, E);
  for(int e=e0+tid; e<e1; e+=256) atomicAdd(&h[dst[e]/NPG], 1);
  __syncthreads();
  for(int i=tid;i<NB;i+=256) histG[blk*NB+i] = h[i];
}

// block per bucket: exclusive scan of histG[:,b] over blocks -> prefT[b][blk], total[b]
__global__ __launch_bounds__(512) void k_colscan(const int* __restrict__ histG,
    int* __restrict__ prefT, int* __restrict__ total){
  __shared__ int s[NBLK];
  int b = blockIdx.x, t = threadIdx.x;
  int v = histG[t*NB + b];
  s[t] = v;
  __syncthreads();
  for(int off=1; off<NBLK; off<<=1){
    int u = (t >= off) ? s[t-off] : 0;
    __syncthreads();
    s[t] += u;
    __syncthreads();
  }
  prefT[b*NBLK + t] = s[t] - v;
  if(t == NBLK-1) total[b] = s[t];
}

// single block: exclusive scan of total[2000] -> bbase[0..2000]
__global__ __launch_bounds__(1024) void k_bscan(const int* __restrict__ total, int* __restrict__ bbase){
  __shared__ int s[1024];
  int t = threadIdx.x;
  int i0 = 2*t, i1 = 2*t+1;
  int x0 = (i0 < NB) ? total[i0] : 0;
  int x1 = (i1 < NB) ? total[i1] : 0;
  int ps = x0 + x1;
  s[t] = ps;
  __syncthreads();
  for(int off=1; off<1024; off<<=1){
    int u = (t >= off) ? s[t-off] : 0;
    __syncthreads();
    s[t] += u;
    __syncthreads();
  }
  int excl = s[t] - ps;
  if(i0 < NB) bbase[i0] = excl;
  if(i1 < NB) bbase[i1] = excl + x0;
  if(t == 1023) bbase[NB] = s[1023];
}

__global__ __launch_bounds__(256) void k_scatter(const int* __restrict__ src, const int* __restrict__ dst,
    const float* __restrict__ ew, const int* __restrict__ prefT, const int* __restrict__ bbase,
    int4* __restrict__ ebuf, int E){
  __shared__ int cur[NB];
  int blk = blockIdx.x, tid = threadIdx.x;
  for(int i=tid;i<NB;i+=256) cur[i] = prefT[i*NBLK + blk] + bbase[i];
  __syncthreads();
  int e0 = blk*CPB, e1 = min(e0+CPB, E);
  for(int e=e0+tid; e<e1; e+=256){
    int d = dst[e];
    int b = d/NPG;
    int pos = atomicAdd(&cur[b], 1);          // LDS atomic
    ebuf[pos] = make_int4(src[e], d, __float_as_int(ew[e]), 0);
  }
}

// block per graph: degree -> dis, row starts, scatter to CSR (int2{src, ew*dis[dst]})
__global__ __launch_bounds__(256) void k_bucket(const int4* __restrict__ ebuf, const int* __restrict__ bbase,
    float* __restrict__ dis, int* __restrict__ rs, int2* __restrict__ csr, int N){
  __shared__ float degw[NPG];
  __shared__ int cnt[NPG];
  __shared__ float disl[NPG];
  __shared__ int cur[NPG];
  __shared__ int sc[128];
  int g = blockIdx.x, tid = threadIdx.x;
  int g0 = g*NPG;
  if(tid < NPG){ degw[tid] = 0.f; cnt[tid] = 0; }
  __syncthreads();
  int e0 = bbase[g], e1 = bbase[g+1];
  for(int e=e0+tid; e<e1; e+=256){
    int4 t = ebuf[e];
    int ld = t.y - g0;
    atomicAdd(&cnt[ld], 1);
    atomicAdd(&degw[ld], __int_as_float(t.z));
  }
  __syncthreads();
  if(tid < NPG){
    float dv = rsqrtf(degw[tid] + 1.0f);      // +1 self loop; deg>=1 so no zero case
    disl[tid] = dv;
    dis[g0+tid] = dv;
  }
  if(tid < 128) sc[tid] = (tid < NPG) ? cnt[tid] : 0;
  __syncthreads();
  for(int off=1; off<128; off<<=1){
    int u = 0;
    if(tid < 128 && tid >= off) u = sc[tid-off];
    __syncthreads();
    if(tid < 128) sc[tid] += u;
    __syncthreads();
  }
  if(tid < NPG){
    int st = e0 + sc[tid] - cnt[tid];         // exclusive start
    cur[tid] = st;
    rs[g0+tid] = st;
  }
  if(g == NB-1 && tid == 0) rs[N] = e1;
  __syncthreads();
  for(int e=e0+tid; e<e1; e+=256){
    int4 t = ebuf[e];
    int ld = t.y - g0;
    int pos = atomicAdd(&cur[ld], 1);         // LDS atomic
    csr[pos] = make_int2(t.x, __float_as_int(__int_as_float(t.z)*disl[ld]));
  }
}

__global__ void k_norm(int2* __restrict__ csr, const float* __restrict__ dis, int E){
  int e = blockIdx.x*256 + threadIdx.x;
  if(e < E){
    int2 p = csr[e];
    p.y = __float_as_int(__int_as_float(p.y)*dis[p.x]);
    csr[e] = p;
  }
}

// ---------------- GEMMs ----------------
__global__ __launch_bounds__(256) void k_gemm1(const int* __restrict__ wI, const int* __restrict__ z1I,
   const int* __restrict__ z2I,
   const float* __restrict__ embw, const float* __restrict__ embz1, const float* __restrict__ embz2,
   const float* __restrict__ W0, float* __restrict__ hx, int N){
  __shared__ __align__(16) float X[128][97];
  __shared__ __align__(16) float Ws[96*32];
  __shared__ int iw[128], i1[128], i2[128];
  int tid = threadIdx.x;
  int g0 = blockIdx.x*128;
  for(int i=tid;i<96*32;i+=256) Ws[i]=W0[i];
  if(tid < 128){
    int gn = g0 + tid;
    bool ok = gn < N;
    iw[tid] = ok ? wI[gn]  : 0;
    i1[tid] = ok ? z1I[gn] : 0;
    i2[tid] = ok ? z2I[gn] : 0;
  }
  __syncthreads();
  for(int r=0;r<48;r++){
    int flat = r*256 + tid;
    int n = flat/96, c = flat - n*96;
    int gn = g0 + n;
    float val = 0.f;
    if(gn < N){
      if(c < 32)      val = embw [iw[n]*32 + c];
      else if(c < 64) val = embz1[i1[n]*32 + (c-32)];
      else            val = embz2[i2[n]*32 + (c-64)];
    }
    X[n][c] = val;
  }
  __syncthreads();
  int ng = tid>>3, chg = tid&7;
  float4 acc[4];
  #pragma unroll
  for(int j=0;j<4;j++) acc[j] = make_float4(0.f,0.f,0.f,0.f);
  #pragma unroll 4
  for(int i=0;i<96;i++){
    float4 wv = *(const float4*)&Ws[i*32 + chg*4];
    #pragma unroll
    for(int j=0;j<4;j++){
      float xv = X[ng*4+j][i];
      acc[j].x += xv*wv.x; acc[j].y += xv*wv.y; acc[j].z += xv*wv.z; acc[j].w += xv*wv.w;
    }
  }
  #pragma unroll
  for(int j=0;j<4;j++){
    int gn = g0 + ng*4 + j;
    if(gn < N) *(float4*)&hx[(size_t)gn*32 + chg*4] = acc[j];
  }
}

__global__ __launch_bounds__(256) void k_gemm32(const float* __restrict__ xin, const float* __restrict__ W,
    float* __restrict__ hx, int N){
  __shared__ __align__(16) float X[128][33];
  __shared__ __align__(16) float Ws[32*32];
  int tid = threadIdx.x;
  int g0 = blockIdx.x*128;
  for(int i=tid;i<1024;i+=256) Ws[i]=W[i];
  for(int r=0;r<16;r++){
    int flat = r*256 + tid;
    int n = flat>>5, c = flat&31;
    int gn = g0 + n;
    X[n][c] = (gn < N) ? xin[(size_t)gn*32 + c] : 0.f;
  }
  __syncthreads();
  int ng = tid>>3, chg = tid&7;
  float4 acc[4];
  #pragma unroll
  for(int j=0;j<4;j++) acc[j] = make_float4(0.f,0.f,0.f,0.f);
  #pragma unroll 4
  for(int i=0;i<32;i++){
    float4 wv = *(const float4*)&Ws[i*32 + chg*4];
    #pragma unroll
    for(int j=0;j<4;j++){
      float xv = X[ng*4+j][i];
      acc[j].x += xv*wv.x; acc[j].y += xv*wv.y; acc[j].z += xv*wv.z; acc[j].w += xv*wv.w;
    }
  }
  #pragma unroll
  for(int j=0;j<4;j++){
    int gn = g0 + ng*4 + j;
    if(gn < N) *(float4*)&hx[(size_t)gn*32 + chg*4] = acc[j];
  }
}

__global__ __launch_bounds__(256) void k_gemmv(const float* __restrict__ xin, const float* __restrict__ W3,
    float* __restrict__ hv, int N){
  __shared__ float X[256][33];
  __shared__ float Ws[32];
  int tid = threadIdx.x;
  int g0 = blockIdx.x*256;
  if(tid < 32) Ws[tid] = W3[tid];
  for(int r=0;r<32;r++){
    int flat = r*256 + tid;
    int n = flat>>5, c = flat&31;
    int gn = g0 + n;
    X[n][c] = (gn < N) ? xin[(size_t)gn*32 + c] : 0.f;
  }
  __syncthreads();
  float acc = 0.f;
  #pragma unroll
  for(int i=0;i<32;i++) acc += X[tid][i]*Ws[i];
  int gn = g0 + tid;
  if(gn < N) hv[gn] = acc;
}

// ---------------- aggregation (gather CSR by dst) ----------------
__global__ __launch_bounds__(256) void k_agg32(const float* __restrict__ hx, const float* __restrict__ dis,
   const int* __restrict__ rs, const int2* __restrict__ csr,
   const float* __restrict__ bias, float* __restrict__ hout, int N){
  int tid = threadIdx.x;
  int ln = tid>>5, ch = tid&31;
  int n = blockIdx.x*8 + ln;
  if(n >= N) return;
  float dn = dis[n];
  float acc = dn*dn*hx[(size_t)n*32 + ch];
  int e0 = rs[n], e1 = rs[n+1];
  for(int e=e0;e<e1;e++){
    int2 p = csr[e];
    acc += __int_as_float(p.y) * hx[(size_t)p.x*32 + ch];
  }
  hout[(size_t)n*32 + ch] = tanhf(acc + bias[ch]);
}

__global__ void k_agg1(const float* __restrict__ hv, const float* __restrict__ dis,
   const int* __restrict__ rs, const int2* __restrict__ csr,
   const float* __restrict__ b3, float* __restrict__ h4, int N){
  int n = blockIdx.x*256 + threadIdx.x;
  if(n >= N) return;
  float dn = dis[n];
  float acc = dn*dn*hv[n];
  int e0 = rs[n], e1 = rs[n+1];
  for(int e=e0;e<e1;e++){
    int2 p = csr[e];
    acc += __int_as_float(p.y)*hv[p.x];
  }
  h4[n] = tanhf(acc + b3[0]);
}

// ---------------- fused head ----------------
__global__ __launch_bounds__(256) void k_head(const float* __restrict__ h1,const float* __restrict__ h2,
  const float* __restrict__ h3,const float* __restrict__ h4,
  const float* __restrict__ c1W,const float* __restrict__ c1b,
  const float* __restrict__ c2W,const float* __restrict__ c2b,
  const float* __restrict__ l1W,const float* __restrict__ l1b,
  const float* __restrict__ l2W,const float* __restrict__ l2b,
  float* __restrict__ out){
  __shared__ float v[100];
  __shared__ int ord[KTOP];
  __shared__ __align__(16) float xk[KTOP][100];
  __shared__ __align__(16) float c1Ws[16*100];
  __shared__ __align__(16) float t1[16][60];
  __shared__ __align__(16) float t2[16][32];
  __shared__ __align__(16) float c2Ws[32*16*5];
  __shared__ __align__(16) float flat[832];
  __shared__ __align__(16) float o1s[2][128];
  int b = blockIdx.x, tid = threadIdx.x;
  int g0 = b*NPG;
  for(int i=tid;i<16*97;i+=256){ int o=i/97, d=i-o*97; c1Ws[o*100+d]=c1W[i]; }
  for(int i=tid;i<2560;i+=256) c2Ws[i]=c2W[i];
  if(tid < 100) v[tid] = h4[g0+tid];
  __syncthreads();
  if(tid < 100){
    float vi = v[tid];
    int rank = 0;
    for(int j=0;j<100;j++){
      float vj = v[j];
      rank += (vj > vi) || (vj == vi && j < tid);
    }
    if(rank < KTOP) ord[rank] = tid;
  }
  __syncthreads();
  for(int idx=tid; idx<KTOP*DLAT; idx+=256){
    int k = idx/DLAT, d = idx - k*DLAT;
    int n = g0 + ord[k];
    float val;
    if(d < 32)      val = h1[(size_t)n*32 + d];
    else if(d < 64) val = h2[(size_t)n*32 + (d-32)];
    else if(d < 96) val = h3[(size_t)n*32 + (d-64)];
    else            val = h4[n];
    xk[k][d] = val;
  }
  __syncthreads();
  if(tid < 120){
    int og = tid/15, kg = tid - og*15;
    float a0[4] = {0,0,0,0}, a1[4] = {0,0,0,0};
    for(int d=0; d<96; d+=4){
      float4 w0 = *(const float4*)&c1Ws[og*100 + d];
      float4 w1 = *(const float4*)&c1Ws[(og+8)*100 + d];
      #pragma unroll
      for(int j=0;j<4;j++){
        float4 xv = *(const float4*)&xk[kg + 15*j][d];
        a0[j] += dot4(xv, w0);
        a1[j] += dot4(xv, w1);
      }
    }
    {
      float w0 = c1Ws[og*100 + 96], w1 = c1Ws[(og+8)*100 + 96];
      #pragma unroll
      for(int j=0;j<4;j++){
        float xv = xk[kg + 15*j][96];
        a0[j] += xv*w0;
        a1[j] += xv*w1;
      }
    }
    float b0v = c1b[og], b1v = c1b[og+8];
    #pragma unroll
    for(int j=0;j<4;j++){
      t1[og  ][kg + 15*j] = fmaxf(a0[j] + b0v, 0.f);
      t1[og+8][kg + 15*j] = fmaxf(a1[j] + b1v, 0.f);
    }
  }
  __syncthreads();
  for(int idx=tid; idx<480; idx+=256){
    int o = idx/30, jj = idx - o*30;
    t2[o][jj] = fmaxf(t1[o][2*jj], t1[o][2*jj+1]);
  }
  __syncthreads();
  if(tid < 224){
    int oc = tid/7, pg = tid - oc*7;
    int p0 = pg*4;
    float acc[4] = {0,0,0,0};
    for(int ic=0; ic<16; ic++){
      float4 A  = *(const float4*)&t2[ic][p0];
      float4 Bv = *(const float4*)&t2[ic][p0+4];
      float e[8] = {A.x,A.y,A.z,A.w,Bv.x,Bv.y,Bv.z,Bv.w};
      const float* wr = &c2Ws[(oc*16 + ic)*5];
      #pragma unroll
      for(int q=0;q<4;q++){
        #pragma unroll
        for(int r=0;r<5;r++) acc[q] += e[q+r]*wr[r];
      }
    }
    float bb = c2b[oc];
    #pragma unroll
    for(int q=0;q<4;q++){
      int p = p0 + q;
      if(p < 26) flat[oc*26 + p] = fmaxf(acc[q] + bb, 0.f);
    }
  }
  __syncthreads();
  {
    int half = tid>>7, j = tid&127;
    int i0 = half*416;
    float s = 0.f;
    #pragma unroll 4
    for(int i=0;i<416;i++){
      s += flat[i0+i] * l1W[(size_t)(i0+i)*128 + j];
    }
    o1s[half][j] = s;
  }
  __syncthreads();
  if(tid < 128){
    float r = o1s[0][tid] + o1s[1][tid] + l1b[tid];
    o1s[0][tid] = fmaxf(r, 0.f);
  }
  __syncthreads();
  float* red = (float*)t1;
  if(tid < 128) red[tid] = o1s[0][tid]*l2W[tid];
  __syncthreads();
  if(tid < 64){
    float val = red[tid] + red[tid+64];
    #pragma unroll
    for(int off=32; off>0; off>>=1) val += __shfl_down(val, off);
    if(tid == 0) out[b] = val + l2b[0];
  }
}

// ---------------- launch ----------------
extern "C" void kernel_launch(void* const* d_in, const int* in_sizes, int n_in,
                              void* d_out, int out_size, void* d_ws, size_t ws_size,
                              hipStream_t stream){
  (void)n_in; (void)out_size; (void)ws_size;
  const int*   z1    = (const int*)  d_in[0];
  const int*   z2    = (const int*)  d_in[1];
  const int*   w     = (const int*)  d_in[2];
  const int*   eidx  = (const int*)  d_in[3];
  const float* ew    = (const float*)d_in[5];
  const float* embw  = (const float*)d_in[6];
  const float* embz1 = (const float*)d_in[7];
  const float* embz2 = (const float*)d_in[8];
  const float* W0    = (const float*)d_in[9];
  const float* b0    = (const float*)d_in[10];
  const float* W1    = (const float*)d_in[11];
  const float* b1    = (const float*)d_in[12];
  const float* W2    = (const float*)d_in[13];
  const float* b2    = (const float*)d_in[14];
  const float* W3    = (const float*)d_in[15];
  const float* b3    = (const float*)d_in[16];
  const float* c1W   = (const float*)d_in[17];
  const float* c1b   = (const float*)d_in[18];
  const float* c2W   = (const float*)d_in[19];
  const float* c2b   = (const float*)d_in[20];
  const float* l1W   = (const float*)d_in[21];
  const float* l1b   = (const float*)d_in[22];
  const float* l2W   = (const float*)d_in[23];
  const float* l2b   = (const float*)d_in[24];
  float* out = (float*)d_out;

  int N = in_sizes[0];
  int E = in_sizes[3]/2;
  int B = N/NPG;
  const int* src = eidx;
  const int* dst = eidx + E;

  char* p = (char*)d_ws;
  auto alloc = [&](size_t bytes)->char*{
    char* r = p;
    p += (bytes + 255) & ~(size_t)255;
    return r;
  };
  float* h1    = (float*)alloc((size_t)N*32*4);
  float* h2    = (float*)alloc((size_t)N*32*4);
  float* h3    = (float*)alloc((size_t)N*32*4);
  float* h4    = (float*)alloc((size_t)N*4);
  float* hx    = (float*)alloc((size_t)N*32*4);
  float* dis   = (float*)alloc((size_t)N*4);
  int*   rs    = (int*)  alloc((size_t)(N+1)*4);
  int*   histG = (int*)  alloc((size_t)NBLK*NB*4);
  int*   prefT = (int*)  alloc((size_t)NB*NBLK*4);
  int*   total = (int*)  alloc((size_t)NB*4);
  int*   bbase = (int*)  alloc((size_t)(NB+1)*4);
  int2*  csr   = (int2*) alloc((size_t)E*8);
  int4*  ebuf  = (int4*)h1;    // alias: 51.2MB fits in h1+h2+h3 (76.8MB); dead before h1 written

  int gE = (E+255)/256;
  k_hist   <<<NBLK, 256, 0, stream>>>(dst, histG, E);
  k_colscan<<<NB,   512, 0, stream>>>(histG, prefT, total);
  k_bscan  <<<1,   1024, 0, stream>>>(total, bbase);
  k_scatter<<<NBLK, 256, 0, stream>>>(src, dst, ew, prefT, bbase, ebuf, E);
  k_bucket <<<B,    256, 0, stream>>>(ebuf, bbase, dis, rs, csr, N);
  k_norm   <<<gE,   256, 0, stream>>>(csr, dis, E);

  int gG = (N+127)/128;
  k_gemm1 <<<gG, 256, 0, stream>>>(w, z1, z2, embw, embz1, embz2, W0, hx, N);
  k_agg32 <<<(N+7)/8, 256, 0, stream>>>(hx, dis, rs, csr, b0, h1, N);
  k_gemm32<<<gG, 256, 0, stream>>>(h1, W1, hx, N);
  k_agg32 <<<(N+7)/8, 256, 0, stream>>>(hx, dis, rs, csr, b1, h2, N);
  k_gemm32<<<gG, 256, 0, stream>>>(h2, W2, hx, N);
  k_agg32 <<<(N+7)/8, 256, 0, stream>>>(hx, dis, rs, csr, b2, h3, N);
  k_gemmv <<<(N+255)/256, 256, 0, stream>>>(h3, W3, hx, N);
  k_agg1  <<<gE==0?1:(N+255)/256, 256, 0, stream>>>(hx, dis, rs, csr, b3, h4, N);

  k_head<<<B, 256, 0, stream>>>(h1, h2, h3, h4, c1W, c1b, c2W, c2b,
                                l1W, l1b, l2W, l2b, out);
}